// Round 1
// baseline (743.620 us; speedup 1.0000x reference)
//
#include <hip/hip_runtime.h>
#include <hip/hip_bf16.h>

#define B_  1024
#define K_  32
#define G_  1024
#define TD_ 100
#define ED_ 128
#define ND_ 128

__device__ __forceinline__ float bf_lo(unsigned u){ union{unsigned q; float f;} c; c.q = u << 16; return c.f; }
__device__ __forceinline__ float bf_hi(unsigned u){ union{unsigned q; float f;} c; c.q = u & 0xFFFF0000u; return c.f; }

template<typename T> __device__ __forceinline__ float ldf(const T* p);
template<> __device__ __forceinline__ float ldf<float>(const float* p){ return *p; }
template<> __device__ __forceinline__ float ldf<__hip_bfloat16>(const __hip_bfloat16* p){
    unsigned short s = *(const unsigned short*)p;
    union{unsigned q; float f;} c; c.q = ((unsigned)s) << 16; return c.f;
}

template<typename T> __device__ __forceinline__ float2 ld2(const T* p);
template<> __device__ __forceinline__ float2 ld2<float>(const float* p){ return *(const float2*)p; }
template<> __device__ __forceinline__ float2 ld2<__hip_bfloat16>(const __hip_bfloat16* p){
    unsigned u = *(const unsigned*)p;
    float2 r; r.x = bf_lo(u); r.y = bf_hi(u); return r;
}

template<typename T> __device__ __forceinline__ T stf(float v);
template<> __device__ __forceinline__ float stf<float>(float v){ return v; }
template<> __device__ __forceinline__ __hip_bfloat16 stf<__hip_bfloat16>(float v){ return __float2bfloat16(v); }

template<typename T>
__global__ __launch_bounds__(256, 4) void fused_tgat(
    const int* __restrict__ node_ids,      // [B]
    const T*   __restrict__ nit,           // [B] node_interact_times
    const int* __restrict__ nbr_ids,       // [B,K]
    const int* __restrict__ nbr_eids,      // [B,K]
    const T*   __restrict__ nbr_t,         // [B,K]
    const int* __restrict__ tg_ids,        // [B,G]
    const T*   __restrict__ nraw,          // [NUM_NODES, ND]
    const T*   __restrict__ eraw,          // [NUM_EDGES, ED]
    const T*   __restrict__ tw,            // [TD]
    const T*   __restrict__ tb,            // [TD]
    const T*   __restrict__ We,            // [ED+TD, ED]
    const T*   __restrict__ be,            // [ED]
    const T*   __restrict__ wf,            // [K]
    const T*   __restrict__ bfin,          // [1]
    const T*   __restrict__ Wn,            // [ED+ND, ND]
    const T*   __restrict__ bn,            // [ND]
    T*         __restrict__ out)           // [B, ND]
{
    constexpr bool BF16 = (sizeof(T) == 2);
    // Runtime dtype gate: time_w[0] == 1.0f. As fp32 the first word is
    // 0x3F800000; as a bf16 pair it is 0x3F513F80. The mismatched
    // instantiation self-disables.
    {
        unsigned w0 = *(const unsigned*)tw;
        bool data_is_f32 = (w0 == 0x3F800000u);
        if (data_is_f32 == BF16) return;
    }
    const int b = blockIdx.x;
    const int t = threadIdx.x;

    __shared__ int   s_ids[G_];            // staged time-gap ids (4 KB)
    __shared__ float s_dt[K_], s_wf[K_], s_wfm[K_];
    __shared__ int   s_eid[K_];
    __shared__ float s_cat[ED_ + TD_];     // weighted-pooled concat (228)
    __shared__ float s_pooled[ED_];
    __shared__ float s_on[ND_];
    __shared__ float s_red[2 * ND_];
    __shared__ int   s_cnt[4];

    // ---- Phase 0: stage time-gap neighbor ids (coalesced int4) ----
    {
        const int4* p = (const int4*)(tg_ids + (size_t)b * G_);
        int4 v = p[t];
        *(int4*)&s_ids[4 * t] = v;
    }
    // ---- Phase A0: per-neighbor scalars ----
    if (t < K_) {
        float ntk = ldf(nbr_t + (size_t)b * K_ + t);
        float itb = ldf(nit + b);
        float wfk = ldf(wf + t);
        int   nid = nbr_ids[(size_t)b * K_ + t];
        s_dt[t]  = itb - ntk;
        s_wf[t]  = wfk;
        s_wfm[t] = (nid == 0) ? 0.0f : wfk;   // time feats masked where nid==0
        s_eid[t] = nbr_eids[(size_t)b * K_ + t];
    }
    __syncthreads();

    // ---- Phase A1: s_cat[j] = sum_k wf[k] * cat[b,k,j]  (pool BEFORE matmul) ----
    if (t < ED_) {
        float acc = 0.0f;
        #pragma unroll 8
        for (int k = 0; k < K_; ++k)
            acc = fmaf(s_wf[k], ldf(eraw + (size_t)s_eid[k] * ED_ + t), acc);
        s_cat[t] = acc;
    } else if (t < ED_ + TD_) {
        int tt = t - ED_;
        float wv = ldf(tw + tt);
        float bv = ldf(tb + tt);
        float acc = 0.0f;
        #pragma unroll 4
        for (int k = 0; k < K_; ++k)
            acc = fmaf(s_wfm[k], cosf(fmaf(s_dt[k], wv, bv)), acc);
        s_cat[t] = acc;
    }
    __syncthreads();

    // ---- Phase A2: pooled = s_cat @ W_edge + (sum wf)*b_edge + b_final ----
    if (t < ED_) {
        float swf = 0.0f;
        #pragma unroll
        for (int k = 0; k < K_; ++k) swf += s_wf[k];
        float acc = fmaf(swf, ldf(be + t), ldf(bfin));
        #pragma unroll 4
        for (int j = 0; j < ED_ + TD_; ++j)
            acc = fmaf(s_cat[j], ldf(We + (size_t)j * ED_ + t), acc);
        s_pooled[t] = acc;
    }
    // no barrier needed here: node phase below doesn't touch s_cat/s_pooled,
    // and barriers inside the node phase order s_pooled before the final phase.

    // ---- Phase B: node branch. softmax(mask) == uniform over valid ids ----
    // wave g-row mapping: group = wave, lane p holds dims {2p, 2p+1}
    const int lane = t & 63;
    const int grp  = t >> 6;
    const int d0   = 2 * lane;
    float a0 = 0.0f, a1 = 0.0f;
    int cnt = 0;
    #pragma unroll 4
    for (int g = grp; g < G_; g += 4) {
        int id = s_ids[g];                 // wave-uniform
        if (id > 0) {
            ++cnt;
            float2 v = ld2(nraw + (size_t)id * ND_ + d0);
            a0 += v.x; a1 += v.y;
        }
    }
    if (grp >= 2) *(float2*)&s_red[(grp - 2) * ND_ + d0] = make_float2(a0, a1);
    if (lane == 0) s_cnt[grp] = cnt;
    __syncthreads();
    if (grp < 2) {
        float2 v = *(const float2*)&s_red[grp * ND_ + d0];
        a0 += v.x; a1 += v.y;
    }
    __syncthreads();
    if (grp == 1) *(float2*)&s_red[d0] = make_float2(a0, a1);
    __syncthreads();
    if (grp == 0) {
        float2 v = *(const float2*)&s_red[d0];
        a0 += v.x; a1 += v.y;
        int nv = s_cnt[0] + s_cnt[1] + s_cnt[2] + s_cnt[3];
        float scale = (nv > 0) ? 1.0f / (1024.0f * (float)nv) : 0.0f;
        int nid = node_ids[b];
        float2 nr = ld2(nraw + (size_t)nid * ND_ + d0);
        s_on[d0]     = fmaf(a0, scale, nr.x);
        s_on[d0 + 1] = fmaf(a1, scale, nr.y);
    }
    __syncthreads();

    // ---- Phase C: emb = [pooled | out_node] @ W_node + b_node ----
    float facc = 0.0f;
    if (t < ND_) {
        #pragma unroll 4
        for (int j = 0; j < ED_; ++j)
            facc = fmaf(s_pooled[j], ldf(Wn + (size_t)j * ND_ + t), facc);
    } else {
        int e = t - ND_;
        #pragma unroll 4
        for (int j = 0; j < ND_; ++j)
            facc = fmaf(s_on[j], ldf(Wn + (size_t)(ED_ + j) * ND_ + e), facc);
        s_red[e] = facc;
    }
    __syncthreads();
    if (t < ND_) {
        float r = facc + s_red[t] + ldf(bn + t);
        out[(size_t)b * ND_ + t] = stf<T>(r);
    }
}

extern "C" void kernel_launch(void* const* d_in, const int* in_sizes, int n_in,
                              void* d_out, int out_size, void* d_ws, size_t ws_size,
                              hipStream_t stream) {
    (void)in_sizes; (void)n_in; (void)out_size; (void)d_ws; (void)ws_size;
    dim3 grid(B_), block(256);
    // Launch both dtype instantiations every call; exactly one self-enables
    // based on the on-device encoding of time_w[0].
    fused_tgat<float><<<grid, block, 0, stream>>>(
        (const int*)d_in[0], (const float*)d_in[1], (const int*)d_in[2],
        (const int*)d_in[3], (const float*)d_in[4], (const int*)d_in[5],
        (const float*)d_in[6], (const float*)d_in[7], (const float*)d_in[8],
        (const float*)d_in[9], (const float*)d_in[10], (const float*)d_in[11],
        (const float*)d_in[12], (const float*)d_in[13], (const float*)d_in[14],
        (const float*)d_in[15], (float*)d_out);
    fused_tgat<__hip_bfloat16><<<grid, block, 0, stream>>>(
        (const int*)d_in[0], (const __hip_bfloat16*)d_in[1], (const int*)d_in[2],
        (const int*)d_in[3], (const __hip_bfloat16*)d_in[4], (const int*)d_in[5],
        (const __hip_bfloat16*)d_in[6], (const __hip_bfloat16*)d_in[7],
        (const __hip_bfloat16*)d_in[8], (const __hip_bfloat16*)d_in[9],
        (const __hip_bfloat16*)d_in[10], (const __hip_bfloat16*)d_in[11],
        (const __hip_bfloat16*)d_in[12], (const __hip_bfloat16*)d_in[13],
        (const __hip_bfloat16*)d_in[14], (const __hip_bfloat16*)d_in[15],
        (__hip_bfloat16*)d_out);
}